// Round 11
// baseline (196.066 us; speedup 1.0000x reference)
//
#include <hip/hip_runtime.h>
#include <hip/hip_bf16.h>
#include <math.h>

#define Bb   16
#define HWn  4096
#define Ff   512
#define Kk   32
#define GCH  64            // n-chunks per b (64 rows per chunk)

typedef __attribute__((ext_vector_type(8))) short  short8;
typedef __attribute__((ext_vector_type(4))) float  f32x4;

// ws layout (float offsets) — small stuff only
#define WS_SSUM  0                          // 512
#define WS_EOUT  512
#define WS_ATTN  (WS_EOUT + Bb * Ff)
#define WS_CWB   (WS_ATTN + Bb * Ff)        // 8192 float slots (16384 bf16)
#define WS_C2    (WS_CWB + 8192)
#define WS_SM    (WS_C2 + 32)

// d_out scratch (float offsets into 33.5M featuremap region)
#define SCR_PART 0                          // 16*64*16384 = 16,777,216
#define SCR_RED  16777216                   // +262,144

static __device__ __forceinline__ unsigned int pack2bf(float a, float b) {
    union { __hip_bfloat162 h; unsigned int u; } p;
    p.h = __float22bfloat162_rn(make_float2(a, b));
    return p.u;
}

// ---------------------------------------------------------------------------
// prep: cw -> bf16; fold c2[k]*sm[k]*log2e and sm[k]*log2e. 1 block, 256 thr.
// ---------------------------------------------------------------------------
__global__ void prep(const float* __restrict__ cw, const float* __restrict__ smth,
                     unsigned short* __restrict__ cwb,
                     float* __restrict__ c2l2, float* __restrict__ sml2)
{
    const int t = threadIdx.x;
    const float4* c4 = (const float4*)cw;
    #pragma unroll
    for (int j = 0; j < 16; ++j) {
        const int i = t + j * 256;
        const float4 v = c4[i];
        *reinterpret_cast<uint2*>(&cwb[i * 4]) =
            make_uint2(pack2bf(v.x, v.y), pack2bf(v.z, v.w));
    }
    const int k = t >> 3, sk = t & 7;
    float p = 0.f;
    #pragma unroll
    for (int j = 0; j < 16; ++j) {
        const float4 v = c4[k * 128 + sk + j * 8];
        p = fmaf(v.x, v.x, fmaf(v.y, v.y, fmaf(v.z, v.z, fmaf(v.w, v.w, p))));
    }
    p += __shfl_xor(p, 1); p += __shfl_xor(p, 2); p += __shfl_xor(p, 4);
    if (sk == 0) {
        const float L2E = 1.4426950408889634f;
        const float sm = smth[k];
        sml2[k] = sm * L2E;
        c2l2[k] = p * sm * L2E;
    }
}

// ---------------------------------------------------------------------------
// enc_fused v3: grid (64, 16) = 1024 blocks, block 512 (8 waves), 64 rows/chunk.
// Phase A: k-split — wave (gr = w&3, kh = w>>2) computes FULL-f logits for
// rows gr*16+col, k-half kh (16 MFMA). kh=0 waves also store the bf16 row
// tile to LDS (XOR-swizzled, data already packed for MFMA). lgx[64][36] gets
// complete logits (b128 write per lane).
// Softmax (r10-proven 8-thr/row): in-register, s written fp32 in-place to lgx.
// Phase B (r9/r10-proven rank-update): x from LDS bf16 (v6-proven swizzled
// read + unpack), s broadcast from lgx. ZERO global loads in phase B.
// ---------------------------------------------------------------------------
__global__ __launch_bounds__(512, 2) void enc_fused(
    const float* __restrict__ x, const unsigned short* __restrict__ cwb,
    const float* __restrict__ c2l2, const float* __restrict__ sml2,
    float* __restrict__ part, float* __restrict__ s_sum)
{
    __shared__ __align__(16) unsigned short fb16[64 * 512];  // 64 KB bf16 x tile
    __shared__ __align__(16) float lgx[64][36];              // 9 KB logits -> s
    __shared__ float x2s[64];
    __shared__ float sm_s[32], c2_s[32];
    __shared__ float swred[8][32];

    const int tid  = threadIdx.x;
    const int wave = tid >> 6, lane = tid & 63;
    const int col  = lane & 15, g = lane >> 4;
    const int b    = blockIdx.y, cx = blockIdx.x;
    const int gr   = wave & 3, kh = wave >> 2;
    const int n_loc = gr * 16 + col;

    if (tid < 32) { sm_s[tid] = sml2[tid]; c2_s[tid] = c2l2[tid]; }

    // ============ Phase A: full-f logits for k-half kh ============
    {
        const float4* xr = (const float4*)(x + ((size_t)b * HWn + cx * 64 + n_loc) * Ff) + g * 2;
        const unsigned short* ap = cwb + (kh * 16 + col) * 512 + g * 8;
        f32x4 c0 = {0.f, 0.f, 0.f, 0.f};
        float px = 0.f;
        #pragma unroll
        for (int fs = 0; fs < 16; ++fs) {
            const float4 v0 = xr[fs * 8];
            const float4 v1 = xr[fs * 8 + 1];
            px = fmaf(v0.x, v0.x, fmaf(v0.y, v0.y, fmaf(v0.z, v0.z, fmaf(v0.w, v0.w, px))));
            px = fmaf(v1.x, v1.x, fmaf(v1.y, v1.y, fmaf(v1.z, v1.z, fmaf(v1.w, v1.w, px))));
            union { uint4 u; short8 s; } bu;
            bu.u = make_uint4(pack2bf(v0.x, v0.y), pack2bf(v0.z, v0.w),
                              pack2bf(v1.x, v1.y), pack2bf(v1.z, v1.w));
            if (kh == 0) {          // stage bf16 x (wave-uniform branch)
                const int idx = n_loc * 512 + (((fs * 4 + g) ^ (n_loc & 7)) << 3);
                *reinterpret_cast<uint4*>(&fb16[idx]) = bu.u;
            }
            const short8 a0 = *(const short8*)(ap + fs * 32);
            c0 = __builtin_amdgcn_mfma_f32_16x16x32_bf16(a0, bu.s, c0, 0, 0, 0);
        }
        px += __shfl_xor(px, 16); px += __shfl_xor(px, 32);   // full-row ||x||^2
        if (kh == 0 && g == 0) x2s[n_loc] = px;
        *reinterpret_cast<f32x4*>(&lgx[n_loc][kh * 16 + g * 4]) = c0;
    }
    __syncthreads();

    // ============ Softmax (8 threads/row, r10-proven) ============
    const int srow = tid >> 3, sf = tid & 7;
    float ssl[4];
    {
        const float x2v = x2s[srow];
        float lg[4];
        #pragma unroll
        for (int r = 0; r < 4; ++r) {
            const int k = sf * 4 + r;
            lg[r] = fmaf(sm_s[k], fmaf(-2.f, lgx[srow][k], x2v), c2_s[k]);
        }
        float m = fmaxf(fmaxf(lg[0], lg[1]), fmaxf(lg[2], lg[3]));
        m = fmaxf(m, __shfl_xor(m, 1));
        m = fmaxf(m, __shfl_xor(m, 2));
        m = fmaxf(m, __shfl_xor(m, 4));
        float e[4], sum = 0.f;
        #pragma unroll
        for (int r = 0; r < 4; ++r) { e[r] = exp2f(lg[r] - m); sum += e[r]; }
        sum += __shfl_xor(sum, 1); sum += __shfl_xor(sum, 2); sum += __shfl_xor(sum, 4);
        const float inv = 1.f / sum;
        #pragma unroll
        for (int r = 0; r < 4; ++r) {
            const float s = e[r] * inv;
            lgx[srow][sf * 4 + r] = s;          // own slots: in-place safe
            ssl[r] = s;
        }
    }
    // per-wave s_sum partial (8 rows per wave; reduce over lane bits 3..5)
    #pragma unroll
    for (int r = 0; r < 4; ++r) {
        float v = ssl[r];
        v += __shfl_xor(v, 8); v += __shfl_xor(v, 16); v += __shfl_xor(v, 32);
        if (lane < 8) swred[wave][lane * 4 + r] = v;
    }
    __syncthreads();
    if (tid < 32) {
        float a = 0.f;
        #pragma unroll
        for (int w = 0; w < 8; ++w) a += swred[w][tid];
        atomicAdd(&s_sum[b * Kk + tid], a);
    }

    // ============ Phase B: rank-update, x from LDS bf16 ============
    float acc[4][8];
    #pragma unroll
    for (int j = 0; j < 4; ++j)
        #pragma unroll
        for (int i = 0; i < 8; ++i) acc[j][i] = 0.f;

    const int kq = wave * 4;
    #pragma unroll 4
    for (int nn = 0; nn < 64; ++nn) {
        const f32x4 sv = *(const f32x4*)&lgx[nn][kq];          // broadcast
        const uint4 u = *(const uint4*)&fb16[nn * 512 + ((lane ^ (nn & 7)) << 3)];
        float fx[8];
        fx[0] = __uint_as_float(u.x << 16);
        fx[1] = __uint_as_float(u.x & 0xffff0000u);
        fx[2] = __uint_as_float(u.y << 16);
        fx[3] = __uint_as_float(u.y & 0xffff0000u);
        fx[4] = __uint_as_float(u.z << 16);
        fx[5] = __uint_as_float(u.z & 0xffff0000u);
        fx[6] = __uint_as_float(u.w << 16);
        fx[7] = __uint_as_float(u.w & 0xffff0000u);
        #pragma unroll
        for (int j = 0; j < 4; ++j) {
            const float sj = sv[j];
            #pragma unroll
            for (int i = 0; i < 8; ++i)
                acc[j][i] = fmaf(sj, fx[i], acc[j][i]);
        }
    }
    // partial writeback: [chunk][k][f] fp32, coalesced float4
    float* basep = part + (size_t)(b * GCH + cx) * (Kk * Ff) +
                   (size_t)(wave * 4) * Ff + lane * 8;
    #pragma unroll
    for (int j = 0; j < 4; ++j) {
        *reinterpret_cast<float4*>(basep + j * Ff) =
            make_float4(acc[j][0], acc[j][1], acc[j][2], acc[j][3]);
        *reinterpret_cast<float4*>(basep + j * Ff + 4) =
            make_float4(acc[j][4], acc[j][5], acc[j][6], acc[j][7]);
    }
}

// ---------------------------------------------------------------------------
// enc_red: sum 64 per-chunk partials -> enc[b][k][f]. grid 1024 x 256.
// ---------------------------------------------------------------------------
__global__ void enc_red(const float* __restrict__ scr, float* __restrict__ outp)
{
    const int idx = blockIdx.x * 256 + threadIdx.x;    // 0 .. 262143
    const int b   = idx >> 14;
    const int rem = idx & 16383;
    const float* p = scr + (size_t)b * GCH * 16384 + rem;
    float a = 0.f;
    #pragma unroll
    for (int c = 0; c < GCH; ++c) a += p[c * 16384];
    outp[idx] = a;
}

// ---------------------------------------------------------------------------
// enc_finish: enc = enc_red - s_sum*cw; BN + ReLU; sum over k; se_loss.
// ---------------------------------------------------------------------------
__global__ void enc_finish(const float* __restrict__ enc_acc,
                           const float* __restrict__ s_sum,
                           const float* __restrict__ cw,
                           const float* __restrict__ gamma,
                           const float* __restrict__ beta,
                           const float* __restrict__ mean,
                           const float* __restrict__ var,
                           const float* __restrict__ se_w,
                           const float* __restrict__ se_b,
                           float* __restrict__ enc_out,
                           float* __restrict__ se_out)
{
    __shared__ float ss[Kk];
    __shared__ float red[8];
    const int b = blockIdx.x, f = threadIdx.x;
    if (f < Kk) ss[f] = s_sum[b * Kk + f];
    __syncthreads();
    const float m  = mean[f];
    const float g  = gamma[f];
    const float bt = beta[f];
    const float iv = rsqrtf(var[f] + 1e-3f);
    float a = 0.f;
    #pragma unroll 4
    for (int k = 0; k < Kk; ++k) {
        float v = enc_acc[((long)b * Kk + k) * Ff + f] - ss[k] * cw[k * Ff + f];
        v = (v - m) * iv * g + bt;
        a += fmaxf(v, 0.f);
    }
    enc_out[b * Ff + f] = a;
    float p = a * se_w[f];
    p += __shfl_down(p, 32); p += __shfl_down(p, 16); p += __shfl_down(p, 8);
    p += __shfl_down(p, 4);  p += __shfl_down(p, 2);  p += __shfl_down(p, 1);
    if ((f & 63) == 0) red[f >> 6] = p;
    __syncthreads();
    if (f == 0) {
        float t = 0.f;
        #pragma unroll
        for (int i = 0; i < 8; ++i) t += red[i];
        se_out[b] = t + se_b[0];
    }
}

// ---------------------------------------------------------------------------
// attn_fc: grid 8 blocks x 512; W column-block read exactly once.
// ---------------------------------------------------------------------------
__global__ void attn_fc(const float* __restrict__ enc_out,
                        const float* __restrict__ W,
                        const float* __restrict__ bias,
                        float* __restrict__ attn)
{
    __shared__ float eo[Bb][Ff];
    const int t = threadIdx.x, fg = blockIdx.x;
    #pragma unroll
    for (int j = 0; j < 4; ++j)
        reinterpret_cast<float4*>(&eo[0][0])[t + j * 512] =
            reinterpret_cast<const float4*>(enc_out)[t + j * 512];
    __syncthreads();
    const int f  = fg * 64 + (t & 63);
    const int b0 = t >> 6;
    float a0 = bias[f], a1 = bias[f];
    #pragma unroll 8
    for (int fp = 0; fp < Ff; ++fp) {
        const float w = W[fp * Ff + f];
        a0 = fmaf(eo[b0][fp],     w, a0);
        a1 = fmaf(eo[b0 + 8][fp], w, a1);
    }
    attn[b0 * Ff + f]       = 1.f / (1.f + expf(-a0));
    attn[(b0 + 8) * Ff + f] = 1.f / (1.f + expf(-a1));
}

// ---------------------------------------------------------------------------
// bcast_mul: featuremaps = attn (broadcast over H,W) * inputs
// ---------------------------------------------------------------------------
__global__ void bcast_mul(const float4* __restrict__ x4,
                          const float* __restrict__ attn,
                          float4* __restrict__ o4)
{
    const int stride = gridDim.x * blockDim.x;
    const int total4 = Bb * HWn * Ff / 4;
    for (int i = blockIdx.x * blockDim.x + threadIdx.x; i < total4; i += stride) {
        const float4 v = x4[i];
        const int f4 = i & 127;
        const int bb = i >> 19;
        const float4 a = *reinterpret_cast<const float4*>(&attn[bb * Ff + f4 * 4]);
        o4[i] = make_float4(v.x * a.x, v.y * a.y, v.z * a.z, v.w * a.w);
    }
}

extern "C" void kernel_launch(void* const* d_in, const int* in_sizes, int n_in,
                              void* d_out, int out_size, void* d_ws, size_t ws_size,
                              hipStream_t stream)
{
    (void)in_sizes; (void)n_in; (void)out_size; (void)ws_size;
    const float* x     = (const float*)d_in[0];
    const float* cw    = (const float*)d_in[1];
    const float* smth  = (const float*)d_in[2];
    const float* gamma = (const float*)d_in[3];
    const float* beta  = (const float*)d_in[4];
    const float* mean  = (const float*)d_in[5];
    const float* var   = (const float*)d_in[6];
    const float* Wenc  = (const float*)d_in[7];
    const float* benc  = (const float*)d_in[8];
    const float* Wse   = (const float*)d_in[9];
    const float* bse   = (const float*)d_in[10];

    float* out = (float*)d_out;
    float* ws  = (float*)d_ws;
    float* ssum = ws + WS_SSUM;
    float* eout = ws + WS_EOUT;
    float* attn = ws + WS_ATTN;
    unsigned short* cwb = (unsigned short*)(ws + WS_CWB);
    float* c2l2 = ws + WS_C2;
    float* sml2 = ws + WS_SM;

    float* scr_part = out + SCR_PART;
    float* scr_red  = out + SCR_RED;

    hipMemsetAsync(ssum, 0, (size_t)Bb * Kk * sizeof(float), stream);
    prep<<<1, 256, 0, stream>>>(cw, smth, cwb, c2l2, sml2);
    enc_fused<<<dim3(GCH, Bb), 512, 0, stream>>>(x, cwb, c2l2, sml2, scr_part, ssum);
    enc_red<<<1024, 256, 0, stream>>>(scr_part, scr_red);
    enc_finish<<<Bb, 512, 0, stream>>>(scr_red, ssum, cw, gamma, beta, mean, var,
                                       Wse, bse, eout, out + (long)Bb * HWn * Ff);
    attn_fc<<<8, 512, 0, stream>>>(eout, Wenc, benc, attn);
    bcast_mul<<<2048, 256, 0, stream>>>((const float4*)x, attn, (float4*)out);
}

// Round 12
// 181.953 us; speedup vs baseline: 1.0776x; 1.0776x over previous
//
#include <hip/hip_runtime.h>
#include <hip/hip_bf16.h>
#include <math.h>

#define Bb   16
#define HWn  4096
#define Ff   512
#define Kk   32
#define GCH  64            // n-chunks per b (64 rows per chunk)

typedef __attribute__((ext_vector_type(8))) short  short8;
typedef __attribute__((ext_vector_type(4))) float  f32x4;

// ws layout (float offsets) — small stuff only
#define WS_SSUM  0                          // 512
#define WS_EOUT  512
#define WS_ATTN  (WS_EOUT + Bb * Ff)
#define WS_CWB   (WS_ATTN + Bb * Ff)        // 8192 float slots (16384 bf16)
#define WS_C2    (WS_CWB + 8192)
#define WS_SM    (WS_C2 + 32)

// d_out scratch (float offsets into 33.5M featuremap region)
#define SCR_PART 0                          // bf16 partials: 16*64*16384*2B = 33.5 MB (8.4M float slots)
#define SCR_RED  16777216                   // +262,144 floats

static __device__ __forceinline__ unsigned int pack2bf(float a, float b) {
    union { __hip_bfloat162 h; unsigned int u; } p;
    p.h = __float22bfloat162_rn(make_float2(a, b));
    return p.u;
}

// ---------------------------------------------------------------------------
// prep: cw -> bf16; fold c2[k]*sm[k]*log2e and sm[k]*log2e. 1 block, 256 thr.
// ---------------------------------------------------------------------------
__global__ void prep(const float* __restrict__ cw, const float* __restrict__ smth,
                     unsigned short* __restrict__ cwb,
                     float* __restrict__ c2l2, float* __restrict__ sml2)
{
    const int t = threadIdx.x;
    const float4* c4 = (const float4*)cw;
    #pragma unroll
    for (int j = 0; j < 16; ++j) {
        const int i = t + j * 256;
        const float4 v = c4[i];
        *reinterpret_cast<uint2*>(&cwb[i * 4]) =
            make_uint2(pack2bf(v.x, v.y), pack2bf(v.z, v.w));
    }
    const int k = t >> 3, sk = t & 7;
    float p = 0.f;
    #pragma unroll
    for (int j = 0; j < 16; ++j) {
        const float4 v = c4[k * 128 + sk + j * 8];
        p = fmaf(v.x, v.x, fmaf(v.y, v.y, fmaf(v.z, v.z, fmaf(v.w, v.w, p))));
    }
    p += __shfl_xor(p, 1); p += __shfl_xor(p, 2); p += __shfl_xor(p, 4);
    if (sk == 0) {
        const float L2E = 1.4426950408889634f;
        const float sm = smth[k];
        sml2[k] = sm * L2E;
        c2l2[k] = p * sm * L2E;
    }
}

// ---------------------------------------------------------------------------
// enc_fused (r10 structure + occupancy fix + bf16 partials):
// grid (64, 16) = 1024 blocks, block 512 (8 waves), 64 rows/chunk, 4 blocks/CU.
// Phase A: f-split quadrants — wave (gr = w>>1, fh = w&1) computes PARTIAL xc
// of rows gr*16+col over f-half fh (8 MFMA steps), -> lgp[fh][n][k] LDS.
// Softmax (8-thr/row): sums halves, s written fp32 in-place to lgp[0].
// Phase B: rank-update over 64 rows, s broadcast from LDS, x from global
// (block-local 128 KB, L2-warm from phase A). Partials out in bf16.
// ---------------------------------------------------------------------------
__global__ __launch_bounds__(512, 4) void enc_fused(
    const float* __restrict__ x, const unsigned short* __restrict__ cwb,
    const float* __restrict__ c2l2, const float* __restrict__ sml2,
    unsigned short* __restrict__ part, float* __restrict__ s_sum)
{
    __shared__ __align__(16) float lgp[2][64][32];     // 16 KB: xc partials, then s
    __shared__ float x2p[2][64];
    __shared__ float sm_s[32], c2_s[32];
    __shared__ float swred[8][32];

    const int tid  = threadIdx.x;
    const int wave = tid >> 6, lane = tid & 63;
    const int col  = lane & 15, g = lane >> 4;
    const int b    = blockIdx.y, cx = blockIdx.x;
    const int gr   = wave >> 1, fh = wave & 1;
    const int n_loc = gr * 16 + col;
    const int n     = cx * 64 + n_loc;

    if (tid < 32) { sm_s[tid] = sml2[tid]; c2_s[tid] = c2l2[tid]; }

    // ============ Phase A: partial logits (f-half per wave) ============
    {
        const float4* xr = (const float4*)(x + ((size_t)b * HWn + n) * Ff) + fh * 64 + g * 2;
        const unsigned short* a0p = cwb + col * 512 + fh * 256 + g * 8;
        const unsigned short* a1p = a0p + 16 * 512;
        f32x4 c0 = {0.f, 0.f, 0.f, 0.f}, c1 = {0.f, 0.f, 0.f, 0.f};
        float px = 0.f;
        #pragma unroll
        for (int fs = 0; fs < 8; ++fs) {
            const float4 v0 = xr[fs * 8];
            const float4 v1 = xr[fs * 8 + 1];
            px = fmaf(v0.x, v0.x, fmaf(v0.y, v0.y, fmaf(v0.z, v0.z, fmaf(v0.w, v0.w, px))));
            px = fmaf(v1.x, v1.x, fmaf(v1.y, v1.y, fmaf(v1.z, v1.z, fmaf(v1.w, v1.w, px))));
            union { uint4 u; short8 s; } bu;
            bu.u = make_uint4(pack2bf(v0.x, v0.y), pack2bf(v0.z, v0.w),
                              pack2bf(v1.x, v1.y), pack2bf(v1.z, v1.w));
            const short8 a0 = *(const short8*)(a0p + fs * 32);
            const short8 a1 = *(const short8*)(a1p + fs * 32);
            c0 = __builtin_amdgcn_mfma_f32_16x16x32_bf16(a0, bu.s, c0, 0, 0, 0);
            c1 = __builtin_amdgcn_mfma_f32_16x16x32_bf16(a1, bu.s, c1, 0, 0, 0);
        }
        px += __shfl_xor(px, 16); px += __shfl_xor(px, 32);   // row partial over f-half
        if (g == 0) x2p[fh][n_loc] = px;
        #pragma unroll
        for (int r = 0; r < 4; ++r) {
            lgp[fh][n_loc][g * 4 + r]      = c0[r];
            lgp[fh][n_loc][16 + g * 4 + r] = c1[r];
        }
    }
    __syncthreads();

    // ============ Softmax (8 threads/row) ============
    const int srow = tid >> 3, sf = tid & 7;
    float ssl[4];
    {
        const float x2v = x2p[0][srow] + x2p[1][srow];
        float lg[4];
        #pragma unroll
        for (int r = 0; r < 4; ++r) {
            const int k = sf * 4 + r;
            const float xc = lgp[0][srow][k] + lgp[1][srow][k];
            lg[r] = fmaf(sm_s[k], fmaf(-2.f, xc, x2v), c2_s[k]);
        }
        float m = fmaxf(fmaxf(lg[0], lg[1]), fmaxf(lg[2], lg[3]));
        m = fmaxf(m, __shfl_xor(m, 1));
        m = fmaxf(m, __shfl_xor(m, 2));
        m = fmaxf(m, __shfl_xor(m, 4));
        float e[4], sum = 0.f;
        #pragma unroll
        for (int r = 0; r < 4; ++r) { e[r] = exp2f(lg[r] - m); sum += e[r]; }
        sum += __shfl_xor(sum, 1); sum += __shfl_xor(sum, 2); sum += __shfl_xor(sum, 4);
        const float inv = 1.f / sum;
        #pragma unroll
        for (int r = 0; r < 4; ++r) {
            const float s = e[r] * inv;
            lgp[0][srow][sf * 4 + r] = s;       // own slots: no hazard
            ssl[r] = s;
        }
    }
    // per-wave s_sum partial (8 rows per wave; reduce over lane bits 3..5)
    #pragma unroll
    for (int r = 0; r < 4; ++r) {
        float v = ssl[r];
        v += __shfl_xor(v, 8); v += __shfl_xor(v, 16); v += __shfl_xor(v, 32);
        if (lane < 8) swred[wave][lane * 4 + r] = v;
    }
    __syncthreads();
    if (tid < 32) {
        float a = 0.f;
        #pragma unroll
        for (int w = 0; w < 8; ++w) a += swred[w][tid];
        atomicAdd(&s_sum[b * Kk + tid], a);
    }

    // ============ Phase B: rank-update streaming (64 rows) ============
    float acc[4][8];
    #pragma unroll
    for (int j = 0; j < 4; ++j)
        #pragma unroll
        for (int i = 0; i < 8; ++i) acc[j][i] = 0.f;

    const int kq = wave * 4;
    const float* s_base = &lgp[0][0][0];               // [64][32] fp32
    const float4* xp = (const float4*)(x + ((size_t)b * HWn + cx * 64) * Ff) + lane * 2;
    #pragma unroll 4
    for (int nn = 0; nn < 64; ++nn) {
        const f32x4 sv = *(const f32x4*)&s_base[nn * 32 + kq];   // broadcast
        const float4 v0 = xp[nn * 128];
        const float4 v1 = xp[nn * 128 + 1];
        const float fx[8] = {v0.x, v0.y, v0.z, v0.w, v1.x, v1.y, v1.z, v1.w};
        #pragma unroll
        for (int j = 0; j < 4; ++j) {
            const float sj = sv[j];
            #pragma unroll
            for (int i = 0; i < 8; ++i)
                acc[j][i] = fmaf(sj, fx[i], acc[j][i]);
        }
    }
    // partial writeback: [chunk][k][f] bf16, coalesced 16B/lane
    unsigned short* basep = part + (size_t)(b * GCH + cx) * (Kk * Ff) +
                            (size_t)(wave * 4) * Ff + lane * 8;
    #pragma unroll
    for (int j = 0; j < 4; ++j) {
        *reinterpret_cast<uint4*>(basep + j * Ff) =
            make_uint4(pack2bf(acc[j][0], acc[j][1]), pack2bf(acc[j][2], acc[j][3]),
                       pack2bf(acc[j][4], acc[j][5]), pack2bf(acc[j][6], acc[j][7]));
    }
}

// ---------------------------------------------------------------------------
// enc_red: sum 64 bf16 per-chunk partials -> enc[b][k][f] fp32. grid 1024x256.
// ---------------------------------------------------------------------------
__global__ void enc_red(const unsigned short* __restrict__ scr, float* __restrict__ outp)
{
    const int idx = blockIdx.x * 256 + threadIdx.x;    // 0 .. 262143
    const int b   = idx >> 14;
    const int rem = idx & 16383;
    const unsigned short* p = scr + (size_t)b * GCH * 16384 + rem;
    float a = 0.f;
    #pragma unroll
    for (int c = 0; c < GCH; ++c)
        a += __uint_as_float(((unsigned int)p[c * 16384]) << 16);
    outp[idx] = a;
}

// ---------------------------------------------------------------------------
// enc_finish: enc = enc_red - s_sum*cw; BN + ReLU; sum over k; se_loss.
// ---------------------------------------------------------------------------
__global__ void enc_finish(const float* __restrict__ enc_acc,
                           const float* __restrict__ s_sum,
                           const float* __restrict__ cw,
                           const float* __restrict__ gamma,
                           const float* __restrict__ beta,
                           const float* __restrict__ mean,
                           const float* __restrict__ var,
                           const float* __restrict__ se_w,
                           const float* __restrict__ se_b,
                           float* __restrict__ enc_out,
                           float* __restrict__ se_out)
{
    __shared__ float ss[Kk];
    __shared__ float red[8];
    const int b = blockIdx.x, f = threadIdx.x;
    if (f < Kk) ss[f] = s_sum[b * Kk + f];
    __syncthreads();
    const float m  = mean[f];
    const float g  = gamma[f];
    const float bt = beta[f];
    const float iv = rsqrtf(var[f] + 1e-3f);
    float a = 0.f;
    #pragma unroll 4
    for (int k = 0; k < Kk; ++k) {
        float v = enc_acc[((long)b * Kk + k) * Ff + f] - ss[k] * cw[k * Ff + f];
        v = (v - m) * iv * g + bt;
        a += fmaxf(v, 0.f);
    }
    enc_out[b * Ff + f] = a;
    float p = a * se_w[f];
    p += __shfl_down(p, 32); p += __shfl_down(p, 16); p += __shfl_down(p, 8);
    p += __shfl_down(p, 4);  p += __shfl_down(p, 2);  p += __shfl_down(p, 1);
    if ((f & 63) == 0) red[f >> 6] = p;
    __syncthreads();
    if (f == 0) {
        float t = 0.f;
        #pragma unroll
        for (int i = 0; i < 8; ++i) t += red[i];
        se_out[b] = t + se_b[0];
    }
}

// ---------------------------------------------------------------------------
// attn_fc: grid 8 blocks x 512; W column-block read exactly once.
// ---------------------------------------------------------------------------
__global__ void attn_fc(const float* __restrict__ enc_out,
                        const float* __restrict__ W,
                        const float* __restrict__ bias,
                        float* __restrict__ attn)
{
    __shared__ float eo[Bb][Ff];
    const int t = threadIdx.x, fg = blockIdx.x;
    #pragma unroll
    for (int j = 0; j < 4; ++j)
        reinterpret_cast<float4*>(&eo[0][0])[t + j * 512] =
            reinterpret_cast<const float4*>(enc_out)[t + j * 512];
    __syncthreads();
    const int f  = fg * 64 + (t & 63);
    const int b0 = t >> 6;
    float a0 = bias[f], a1 = bias[f];
    #pragma unroll 8
    for (int fp = 0; fp < Ff; ++fp) {
        const float w = W[fp * Ff + f];
        a0 = fmaf(eo[b0][fp],     w, a0);
        a1 = fmaf(eo[b0 + 8][fp], w, a1);
    }
    attn[b0 * Ff + f]       = 1.f / (1.f + expf(-a0));
    attn[(b0 + 8) * Ff + f] = 1.f / (1.f + expf(-a1));
}

// ---------------------------------------------------------------------------
// bcast_mul: featuremaps = attn (broadcast over H,W) * inputs
// ---------------------------------------------------------------------------
__global__ void bcast_mul(const float4* __restrict__ x4,
                          const float* __restrict__ attn,
                          float4* __restrict__ o4)
{
    const int stride = gridDim.x * blockDim.x;
    const int total4 = Bb * HWn * Ff / 4;
    for (int i = blockIdx.x * blockDim.x + threadIdx.x; i < total4; i += stride) {
        const float4 v = x4[i];
        const int f4 = i & 127;
        const int bb = i >> 19;
        const float4 a = *reinterpret_cast<const float4*>(&attn[bb * Ff + f4 * 4]);
        o4[i] = make_float4(v.x * a.x, v.y * a.y, v.z * a.z, v.w * a.w);
    }
}

extern "C" void kernel_launch(void* const* d_in, const int* in_sizes, int n_in,
                              void* d_out, int out_size, void* d_ws, size_t ws_size,
                              hipStream_t stream)
{
    (void)in_sizes; (void)n_in; (void)out_size; (void)ws_size;
    const float* x     = (const float*)d_in[0];
    const float* cw    = (const float*)d_in[1];
    const float* smth  = (const float*)d_in[2];
    const float* gamma = (const float*)d_in[3];
    const float* beta  = (const float*)d_in[4];
    const float* mean  = (const float*)d_in[5];
    const float* var   = (const float*)d_in[6];
    const float* Wenc  = (const float*)d_in[7];
    const float* benc  = (const float*)d_in[8];
    const float* Wse   = (const float*)d_in[9];
    const float* bse   = (const float*)d_in[10];

    float* out = (float*)d_out;
    float* ws  = (float*)d_ws;
    float* ssum = ws + WS_SSUM;
    float* eout = ws + WS_EOUT;
    float* attn = ws + WS_ATTN;
    unsigned short* cwb = (unsigned short*)(ws + WS_CWB);
    float* c2l2 = ws + WS_C2;
    float* sml2 = ws + WS_SM;

    unsigned short* scr_part = (unsigned short*)(out + SCR_PART);
    float* scr_red  = out + SCR_RED;

    hipMemsetAsync(ssum, 0, (size_t)Bb * Kk * sizeof(float), stream);
    prep<<<1, 256, 0, stream>>>(cw, smth, cwb, c2l2, sml2);
    enc_fused<<<dim3(GCH, Bb), 512, 0, stream>>>(x, cwb, c2l2, sml2, scr_part, ssum);
    enc_red<<<1024, 256, 0, stream>>>(scr_part, scr_red);
    enc_finish<<<Bb, 512, 0, stream>>>(scr_red, ssum, cw, gamma, beta, mean, var,
                                       Wse, bse, eout, out + (long)Bb * HWn * Ff);
    attn_fc<<<8, 512, 0, stream>>>(eout, Wenc, benc, attn);
    bcast_mul<<<2048, 256, 0, stream>>>((const float4*)x, attn, (float4*)out);
}